// Round 5
// baseline (475.326 us; speedup 1.0000x reference)
//
#include <hip/hip_runtime.h>
#include <cstdint>

// x: [4,4096,4096] fp32 -> rows of 128 over [T=16384, N_BANKS=32, BANK=128]
// scores = |x| + bias[bank][:]; mask = top-16 per row (ties -> lowest index);
// out0 = x * mask; out1 = num_assigned_tokens (pass-through).
//
// Session findings:
//  - float4 2-row pair layout: 195-199us (rounds 1-2) -- do not reintroduce.
//  - SALU scalarization of ballot-count logic: 188us (round 3). VGPR-pin
//    (empty asm "+v") keeps counting on the VALU (4 SIMDs/CU vs 1 SALU/CU).
//  - Round 4 (VALU-counted, float2): ~119us kernel. Remaining gap to the
//    ~84-95us memory floor is serialized latency: dependent scalar tail
//    (E~2.2 ballot round-trips) + 1-deep prefetch. This round: level-2
//    parallel probes (tail E -> ~0.7), ex-flag recon skip, 2-deep prefetch.
#define BANKSZ   128
#define N_BANKS  32
#define TOPK     16
#define N_TOKENS (4 * 4096)
#define N_ROWS   (N_TOKENS * N_BANKS)           // 524288
#define OUT0_SZ  (N_TOKENS * N_BANKS * BANKSZ)  // 67108864
#define NAT_SZ   4096

#define NBLK          2048
#define WAVES_TOTAL   (NBLK * 4)                 // 8192
#define ROWS_PER_WAVE (N_ROWS / WAVES_TOTAL)     // 64

// Force a wave-uniform 64-bit value into VGPRs and make it opaque to
// uniformity analysis: downstream __popcll becomes v_bcnt_u32_b32 (VALU)
// instead of s_bcnt1_b64 (SALU), and dependent arithmetic stays VALU.
__device__ __forceinline__ unsigned long long vgpr_pin(unsigned long long m) {
    asm("" : "+v"(m));
    return m;
}

// One wave per row per iteration; lane L holds elements 2L, 2L+1.
// Persistent waves: 64 rows per wave (stride 8192 rows), two-row-ahead
// prefetch. Bank index invariant along the stride, bias loaded once.
//
// Threshold = any key T with |{k : k >= T}| == 16 (ties handled separately).
// Level 1: 6 issue-parallel VALU-counted seed probes at uniformly spaced
// keys S_i = 0xBF880000 + i*0x140000 (floats 1.21875..2.0) bracket the
// |N(0,1)| 16-of-128 order statistic; bracket selection is pure arithmetic
// (j = #(c_i>=16), counts monotone). Level 2: 3 parallel probes at the
// 1/4,1/2,3/4 points of the bracket (one more dependent round) -> bracket
// shrinks 4x and the exact-count collapse (c==16 -> probe IS a valid
// threshold) fires for most rows. Short scalar bisection tail mops up.
// Exact for ANY data; only speed is distribution-tuned.
__global__ __launch_bounds__(256) void balanced_topk_kernel(
    const float* __restrict__ x,
    const float* __restrict__ bias,
    const float* __restrict__ nat,
    float* __restrict__ out)
{
    const int lane = threadIdx.x & 63;
    const int wid  = (blockIdx.x << 2) | (threadIdx.x >> 6);   // 0..8191

    // second output: pass-through, handled by the first 16 blocks
    if (blockIdx.x < (NAT_SZ / 256)) {
        const int i = blockIdx.x * 256 + threadIdx.x;
        out[(size_t)OUT0_SZ + i] = nat[i];
    }

    // bank of every row this wave touches: (wid + i*8192) & 31 == wid & 31
    const int bank = wid & (N_BANKS - 1);
    const float2 bv = ((const float2*)(bias + (size_t)bank * BANKSZ))[lane];

    const float2* __restrict__ x2 = (const float2*)x;
    float2*       __restrict__ o2 = (float2*)out;

    uint32_t idx = (uint32_t)wid * 64u + (uint32_t)lane;  // float2 index
    const uint32_t stride = (uint32_t)WAVES_TOTAL * 64u;  // 524288 float2/iter

    // 2-deep software prefetch: two loads in flight at all times
    float2 v0 = x2[idx];
    float2 v1 = x2[idx + stride];

    for (int i = 0; i < ROWS_PER_WAVE; ++i) {
        const float2  vc  = v0;
        const uint32_t cur = idx;
        v0 = v1;
        idx += stride;
        if (i + 2 < ROWS_PER_WAVE) v1 = x2[idx + stride];

        const float s0 = fabsf(vc.x) + bv.x;
        const float s1 = fabsf(vc.y) + bv.y;

        // monotone float->uint key (exact for negative scores too)
        const uint32_t u0 = __float_as_uint(s0);
        const uint32_t u1 = __float_as_uint(s1);
        const uint32_t k0 = u0 ^ (uint32_t)(((int32_t)u0 >> 31) | 0x80000000);
        const uint32_t k1 = u1 ^ (uint32_t)(((int32_t)u1 >> 31) | 0x80000000);

        // VALU-counted probe: v_cmp ballots + v_bcnt popcounts (no SALU)
#define VCNT(Q) ((uint32_t)(__popcll(vgpr_pin(__ballot(k0 >= (Q)))) \
                          + __popcll(vgpr_pin(__ballot(k1 >= (Q))))))

        // ---- level 1: 6 seed probes, keys S_i = 0xBF880000 + i*0x140000
        const uint32_t c1 = VCNT(0xBF9C0000u);   // 1.21875
        const uint32_t c2 = VCNT(0xBFB00000u);   // 1.375
        const uint32_t c3 = VCNT(0xBFC40000u);   // 1.53125
        const uint32_t c4 = VCNT(0xBFD80000u);   // 1.6875
        const uint32_t c5 = VCNT(0xBFEC0000u);   // 1.84375
        const uint32_t c6 = VCNT(0xC0000000u);   // 2.0

        // j = #(c_i >= 16): arithmetic flags ((c+112)>>7 is 1 iff c>=16)
        const uint32_t j = ((c1 + 112u) >> 7) + ((c2 + 112u) >> 7)
                         + ((c3 + 112u) >> 7) + ((c4 + 112u) >> 7)
                         + ((c5 + 112u) >> 7) + ((c6 + 112u) >> 7);

        // LO = S_j (invariant cnt(LO) >= 16), HI = S_{j+1} (cnt(HI) < 16)
        const uint32_t off = (j << 20) + (j << 18);      // j * 0x140000
        uint32_t LOv = 0xBF880000u + off;
        LOv = (j == 0u) ? 0u : LOv;               // j==0: cnt(0)=128>=16 ok
        uint32_t HIv = 0xBF9C0000u + off;         // = LO + 0x140000
        HIv = (j == 6u) ? 0xFFFFFFFFu : HIv;      // j==6: cnt(~0)=0 < 16 ok

        // ---- level 2: 3 parallel probes at quarter points of [LO, HI)
        const uint32_t step = (HIv - LOv) >> 2;
        const uint32_t Q1 = LOv + step;
        const uint32_t Q2 = Q1 + step;
        const uint32_t Q3 = Q2 + step;
        const uint32_t d1 = VCNT(Q1);
        const uint32_t d2 = VCNT(Q2);
        const uint32_t d3 = VCNT(Q3);
#undef VCNT
        // counts monotone decreasing: j2 = #(d_m >= 16) in {0..3}
        const uint32_t j2 = ((d1 + 112u) >> 7) + ((d2 + 112u) >> 7)
                          + ((d3 + 112u) >> 7);
        uint32_t LO2 = LOv + j2 * step;                 // j2==0 -> LOv
        uint32_t HI2 = (j2 == 3u) ? HIv : (LO2 + step); // j2<3 -> next probe
        // exact-count collapse: count(Q)==16 -> Q is a valid threshold
        uint32_t exu = 0u;
        if (d1 == 16u) { LO2 = Q1; HI2 = Q1 + 1u; exu = 1u; }
        if (d2 == 16u) { LO2 = Q2; HI2 = Q2 + 1u; exu = 1u; }
        if (d3 == 16u) { LO2 = Q3; HI2 = Q3 + 1u; exu = 1u; }

        uint32_t LO = (uint32_t)__builtin_amdgcn_readfirstlane(LO2);
        uint32_t HI = (uint32_t)__builtin_amdgcn_readfirstlane(HI2);
        bool exf = __builtin_amdgcn_readfirstlane(exu) != 0u;

        // dependent scalar tail (E ~ 0.7 iters): cnt(LO) >= 16 > cnt(HI)
#define CNT(Q) (__popcll(__ballot(k0 >= (Q))) + __popcll(__ballot(k1 >= (Q))))
        while (HI - LO > 1u) {
            const uint32_t Q = LO + ((HI - LO) >> 1);
            const int c = CNT(Q);
            if (c == TOPK)      { LO = Q; HI = Q + 1u; exf = true; }
            else if (c > TOPK)  { LO = Q; }
            else                { HI = Q; }
        }
        const uint32_t T = LO;   // separating threshold for the top 16
#undef CNT

        float2 o;
        if (exf) {
            // some probe counted exactly 16: {k >= T} has exactly 16
            // elements, no straddling ties -> pure per-lane select
            o.x = (k0 >= T) ? vc.x : 0.0f;
            o.y = (k1 >= T) ? vc.y : 0.0f;
        } else {
            const unsigned long long g0 = __ballot(k0 >= T);
            const unsigned long long g1 = __ballot(k1 >= T);
            const int cge = __popcll(g0) + __popcll(g1);
            if (cge == TOPK) {
                o.x = (k0 >= T) ? vc.x : 0.0f;
                o.y = (k1 >= T) ? vc.y : 0.0f;
            } else {
                // bit-level ties at T: fill remaining r slots in index order
                const unsigned long long e0 = __ballot(k0 == T);
                const unsigned long long e1 = __ballot(k1 == T);
                const int r = TOPK - (cge - (__popcll(e0) + __popcll(e1)));
                const unsigned long long lt = (1ull << lane) - 1ull;
                const int rank0 = __popcll(e0 & lt) + __popcll(e1 & lt);
                const int rank1 = rank0 + ((k0 == T) ? 1 : 0);
                const bool sel0 = (k0 > T) || ((k0 == T) && (rank0 < r));
                const bool sel1 = (k1 > T) || ((k1 == T) && (rank1 < r));
                o.x = sel0 ? vc.x : 0.0f;
                o.y = sel1 ? vc.y : 0.0f;
            }
        }
        o2[cur] = o;
    }
}

extern "C" void kernel_launch(void* const* d_in, const int* in_sizes, int n_in,
                              void* d_out, int out_size, void* d_ws, size_t ws_size,
                              hipStream_t stream) {
    const float* x    = (const float*)d_in[0];
    const float* bias = (const float*)d_in[1];
    const float* nat  = (const float*)d_in[2];
    float* out = (float*)d_out;

    balanced_topk_kernel<<<dim3(NBLK), dim3(256), 0, stream>>>(x, bias, nat, out);
}

// Round 6
// 439.056 us; speedup vs baseline: 1.0826x; 1.0826x over previous
//
#include <hip/hip_runtime.h>
#include <cstdint>

// x: [4,4096,4096] fp32 -> rows of 128 over [T=16384, N_BANKS=32, BANK=128]
// scores = |x| + bias[bank][:]; mask = top-16 per row (ties -> lowest index);
// out0 = x * mask; out1 = num_assigned_tokens (pass-through).
//
// Session findings (do not regress):
//  - float4 2-row pair layout: 195-199us (r1-2). Keep float2 1-row.
//  - All-SALU counting: SALU is 1 pipe/CU shared by 4 SIMDs; 10 probes ->
//    188us (r3). All-VALU with pin-movs: 13 instr/probe; 9 probes -> 179us
//    at 73% VALUBusy (r5). PROBES ARE THE COST; the serial tail's latency
//    hides under 8-wave TLP. Minimize probes AND per-probe instrs, balance
//    SALU vs VALU.
//  - This round: 5 probes, 6 VALU instr each (inline-asm v_bcnt reading
//    ballot SGPRs directly -- no pin movs), bracket/tail/recon on SALU.
#define BANKSZ   128
#define N_BANKS  32
#define TOPK     16
#define N_TOKENS (4 * 4096)
#define N_ROWS   (N_TOKENS * N_BANKS)           // 524288
#define OUT0_SZ  (N_TOKENS * N_BANKS * BANKSZ)  // 67108864
#define NAT_SZ   4096

#define NBLK          2048
#define WAVES_TOTAL   (NBLK * 4)                 // 8192
#define ROWS_PER_WAVE (N_ROWS / WAVES_TOTAL)     // 64

// Count set bits of two 64-bit ballot masks (4 SGPRs) into one VGPR using
// a v_bcnt accumulate chain: 4 VALU instrs, zero movs, zero SALU.
// (v_bcnt_u32_b32 src0 may be SGPR; one SGPR read per instr -- legal.)
__device__ __forceinline__ uint32_t vbcnt4(unsigned long long m0,
                                           unsigned long long m1) {
    uint32_t r;
    asm("v_bcnt_u32_b32 %0, %1, 0\n\t"
        "v_bcnt_u32_b32 %0, %2, %0\n\t"
        "v_bcnt_u32_b32 %0, %3, %0\n\t"
        "v_bcnt_u32_b32 %0, %4, %0"
        : "=v"(r)
        : "s"((uint32_t)m0), "s"((uint32_t)(m0 >> 32)),
          "s"((uint32_t)m1), "s"((uint32_t)(m1 >> 32)));
    return r;
}

// One wave per row per iteration; lane L holds elements 2L, 2L+1.
// Persistent waves: 64 rows per wave (stride 8192 rows), 2-deep prefetch.
// Bank index invariant along the stride, bias loaded once.
//
// Threshold = any key T with |{k : k >= T}| == 16 (ties via recon path).
// 5 issue-parallel seed probes P_i = 0xBFA00000 + (i-1)*0x140000 (floats
// 1.25..1.875) bracket the |N(0,1)| 16-of-128 order statistic (mean ~1.53,
// sd ~0.115; P(outside) ~ 0.9%). j = #(c_i >= 16) (counts monotone), then
// LO = P_j (j=0 -> 0), HI = P_{j+1} (j=5 -> ~0u) -- exact backstops for ANY
// data. Short SALU bisection tail; for distinct keys it always terminates
// via the count==16 collapse (ex), so the recon ballots are skipped.
__global__ __launch_bounds__(256) void balanced_topk_kernel(
    const float* __restrict__ x,
    const float* __restrict__ bias,
    const float* __restrict__ nat,
    float* __restrict__ out)
{
    const int lane = threadIdx.x & 63;
    const int wid  = (blockIdx.x << 2) | (threadIdx.x >> 6);   // 0..8191

    // second output: pass-through, handled by the first 16 blocks
    if (blockIdx.x < (NAT_SZ / 256)) {
        const int i = blockIdx.x * 256 + threadIdx.x;
        out[(size_t)OUT0_SZ + i] = nat[i];
    }

    // bank of every row this wave touches: (wid + i*8192) & 31 == wid & 31
    const int bank = wid & (N_BANKS - 1);
    const float2 bv = ((const float2*)(bias + (size_t)bank * BANKSZ))[lane];

    const float2* __restrict__ x2 = (const float2*)x;
    float2*       __restrict__ o2 = (float2*)out;

    uint32_t idx = (uint32_t)wid * 64u + (uint32_t)lane;  // float2 index
    const uint32_t stride = (uint32_t)WAVES_TOTAL * 64u;  // 524288 float2/iter

    // 2-deep software prefetch: two loads in flight at all times
    float2 v0 = x2[idx];
    float2 v1 = x2[idx + stride];

    for (int i = 0; i < ROWS_PER_WAVE; ++i) {
        const float2  vc  = v0;
        const uint32_t cur = idx;
        v0 = v1;
        idx += stride;
        if (i + 2 < ROWS_PER_WAVE) v1 = x2[idx + stride];

        const float s0 = fabsf(vc.x) + bv.x;   // v_add_f32 with |src| mod
        const float s1 = fabsf(vc.y) + bv.y;

        // monotone float->uint key (exact for negative scores too)
        const uint32_t u0 = __float_as_uint(s0);
        const uint32_t u1 = __float_as_uint(s1);
        const uint32_t k0 = u0 ^ (uint32_t)(((int32_t)u0 >> 31) | 0x80000000);
        const uint32_t k1 = u1 ^ (uint32_t)(((int32_t)u1 >> 31) | 0x80000000);

        // probe: 2 v_cmp (ballot) + 4 v_bcnt = 6 VALU instrs, result VGPR
#define VCNT(Q) vbcnt4(__ballot(k0 >= (Q)), __ballot(k1 >= (Q)))

        // 5 seed probes, keys P_i = 0xBFA00000 + (i-1)*0x140000
        const uint32_t c1 = VCNT(0xBFA00000u);   // 1.25
        const uint32_t c2 = VCNT(0xBFB40000u);   // 1.40625
        const uint32_t c3 = VCNT(0xBFC80000u);   // 1.5625
        const uint32_t c4 = VCNT(0xBFDC0000u);   // 1.71875
        const uint32_t c5 = VCNT(0xBFF00000u);   // 1.875
#undef VCNT

        // j = #(c_i >= 16): (c+112)>>7 is 1 iff c>=16 (c<=128)  [VALU]
        const uint32_t j = ((c1 + 112u) >> 7) + ((c2 + 112u) >> 7)
                         + ((c3 + 112u) >> 7) + ((c4 + 112u) >> 7)
                         + ((c5 + 112u) >> 7);
        // exm==0 iff some c_i == 16 (then c_j == 16 by monotonicity, and
        // LO = P_j is already a valid exact threshold)
        const uint32_t exm = min(min(min(c1 ^ 16u, c2 ^ 16u),
                                     min(c3 ^ 16u, c4 ^ 16u)), c5 ^ 16u);

        // hand off to SALU: bracket math, tail, recon are wave-uniform
        const uint32_t js  = (uint32_t)__builtin_amdgcn_readfirstlane(j);
        const uint32_t exs = (uint32_t)__builtin_amdgcn_readfirstlane(exm);

        const uint32_t lobase = 0xBF8C0000u + js * 0x140000u;
        uint32_t HI = (js == 5u) ? 0xFFFFFFFFu : (lobase + 0x140000u);
        uint32_t LO = (js == 0u) ? 0u : lobase;
        bool exf = (exs == 0u);

        // SALU bisection tail (skipped when exf; for distinct keys it
        // terminates via the c==16 collapse): cnt(LO) >= 16 > cnt(HI)
#define CNT(Q) (__popcll(__ballot(k0 >= (Q))) + __popcll(__ballot(k1 >= (Q))))
        while (!exf && (HI - LO > 1u)) {
            const uint32_t Q = LO + ((HI - LO) >> 1);
            const int c = CNT(Q);
            if (c == TOPK)      { LO = Q; exf = true; }
            else if (c > TOPK)  { LO = Q; }
            else                { HI = Q; }
        }
        const uint32_t T = LO;   // separating threshold for the top 16
#undef CNT

        float2 o;
        if (exf) {
            // cnt(T) == 16 exactly: no straddling ties, pure per-lane select
            o.x = (k0 >= T) ? vc.x : 0.0f;
            o.y = (k1 >= T) ? vc.y : 0.0f;
        } else {
            const unsigned long long g0 = __ballot(k0 >= T);
            const unsigned long long g1 = __ballot(k1 >= T);
            const int cge = __popcll(g0) + __popcll(g1);
            if (cge == TOPK) {
                o.x = (k0 >= T) ? vc.x : 0.0f;
                o.y = (k1 >= T) ? vc.y : 0.0f;
            } else {
                // bit-level ties at T: fill remaining r slots in index order
                const unsigned long long e0 = __ballot(k0 == T);
                const unsigned long long e1 = __ballot(k1 == T);
                const int r = TOPK - (cge - (__popcll(e0) + __popcll(e1)));
                const unsigned long long lt = (1ull << lane) - 1ull;
                const int rank0 = __popcll(e0 & lt) + __popcll(e1 & lt);
                const int rank1 = rank0 + ((k0 == T) ? 1 : 0);
                const bool sel0 = (k0 > T) || ((k0 == T) && (rank0 < r));
                const bool sel1 = (k1 > T) || ((k1 == T) && (rank1 < r));
                o.x = sel0 ? vc.x : 0.0f;
                o.y = sel1 ? vc.y : 0.0f;
            }
        }
        o2[cur] = o;
    }
}

extern "C" void kernel_launch(void* const* d_in, const int* in_sizes, int n_in,
                              void* d_out, int out_size, void* d_ws, size_t ws_size,
                              hipStream_t stream) {
    const float* x    = (const float*)d_in[0];
    const float* bias = (const float*)d_in[1];
    const float* nat  = (const float*)d_in[2];
    float* out = (float*)d_out;

    balanced_topk_kernel<<<dim3(NBLK), dim3(256), 0, stream>>>(x, bias, nat, out);
}